// Round 16
// baseline (567.243 us; speedup 1.0000x reference)
//
#include <hip/hip_runtime.h>
#include <hip/hip_bf16.h>
#include <math.h>

#define BCAP 128  // per-node edge bin capacity (mean deg 32, P(>128) ~ 0)

__device__ __forceinline__ float wave_reduce_sum(float v) {
#pragma unroll
  for (int m = 32; m > 0; m >>= 1) v += __shfl_xor(v, m, 64);
  return v;
}
__device__ __forceinline__ float wave_reduce_max(float v) {
#pragma unroll
  for (int m = 32; m > 0; m >>= 1) v = fmaxf(v, __shfl_xor(v, m, 64));
  return v;
}

// ---------------- zero fill (float4) ----------------
__global__ void zero_kernel(float4* __restrict__ p, int n4) {
  int i = blockIdx.x * blockDim.x + threadIdx.x;
  int stride = gridDim.x * blockDim.x;
  float4 z = make_float4(0.f, 0.f, 0.f, 0.f);
  for (; i < n4; i += stride) p[i] = z;
}

__global__ void init_counters_kernel(int* __restrict__ cnt, int* __restrict__ cnt0, int N) {
  int i = blockIdx.x * blockDim.x + threadIdx.x;
  if (i < N) { cnt[i] = 0; cnt0[i] = 0; }
}

// ---------------- K1: per-node head/tail gates ----------------
__global__ void node_gate_kernel(const float* __restrict__ h,
                                 const float* __restrict__ Wh,
                                 const float* __restrict__ Wt,
                                 float* __restrict__ eh, float* __restrict__ et,
                                 int N) {
  int v = (blockIdx.x * blockDim.x + threadIdx.x) >> 6;
  int lane = threadIdx.x & 63;
  if (v >= N) return;
  float2 hv = *(const float2*)(h + (size_t)v * 128 + 2 * lane);
  float2 wh = *(const float2*)(Wh + 2 * lane);
  float2 wt = *(const float2*)(Wt + 2 * lane);
  float ah = hv.x * wh.x + hv.y * wh.y;
  float at = hv.x * wt.x + hv.y * wt.y;
  ah = wave_reduce_sum(ah);
  at = wave_reduce_sum(at);
  if (lane == 0) {
    eh[v] = tanhf(ah);
    et[v] = tanhf(at);
  }
}

// ---------------- K2: fused edge kernel, burst-collected epilogue ----------------
// PROBE: entire body runs twice in one dispatch. Pass 0 -> scratch cnt0/bins0
// (identical instruction mix, incl. atomics); pass 1 -> real cnt/bins.
// Surfaces edge in top-5 (~2x dur) with clean per-dispatch counters.
__global__ __launch_bounds__(256) void edge_logit_kernel(
    const float* __restrict__ r, const float* __restrict__ Wr,
    const float* __restrict__ eh, const float* __restrict__ et,
    const int* __restrict__ src, const int* __restrict__ dst,
    int* __restrict__ cnt0, float2* __restrict__ bins0,
    int* __restrict__ cnt, float2* __restrict__ bins,
    int E, int nwaves, int npg) {
  int wid = (blockIdx.x * blockDim.x + threadIdx.x) >> 6;
  int grp = (threadIdx.x >> 5) & 1;
  int gl = threadIdx.x & 31;
  int tOwn = gl >> 2, jOwn = gl & 3;
  const float4* r4 = (const float4*)r;
  float4 w4 = ((const float4*)Wr)[gl];
  int step = nwaves * 8;
  int e0 = wid * 8 + grp * 4;
  if (e0 >= E) return;
  for (int pass = 0; pass < 2; ++pass) {
    int* ct = (pass == 0) ? cnt0 : cnt;
    float2* bn = (pass == 0) ? bins0 : bins;
    size_t rb = (size_t)e0 * 32 + gl;
    float4 v0 = r4[rb];
    float4 v1 = r4[rb + 32];
    float4 v2 = r4[rb + 64];
    float4 v3 = r4[rb + 96];
    for (int bb = e0; bb < E; bb += step * 8) {
      float sOwn = 0.f;
      int eOwn = -1;
#pragma unroll
      for (int t = 0; t < 8; ++t) {
        int ebase = bb + t * step;
        if (ebase < E) {
          int enext = ebase + step;
          float4 n0 = make_float4(0.f, 0.f, 0.f, 0.f), n1 = n0, n2 = n0, n3 = n0;
          if (enext < E) {
            size_t nb = (size_t)enext * 32 + gl;
            n0 = r4[nb];
            n1 = r4[nb + 32];
            n2 = r4[nb + 64];
            n3 = r4[nb + 96];
          }
          float s0 = v0.x * w4.x + v0.y * w4.y + v0.z * w4.z + v0.w * w4.w;
          float s1 = v1.x * w4.x + v1.y * w4.y + v1.z * w4.z + v1.w * w4.w;
          float s2 = v2.x * w4.x + v2.y * w4.y + v2.z * w4.z + v2.w * w4.w;
          float s3 = v3.x * w4.x + v3.y * w4.y + v3.z * w4.z + v3.w * w4.w;
#pragma unroll
          for (int m = 16; m > 0; m >>= 1) {
            s0 += __shfl_xor(s0, m, 32);
            s1 += __shfl_xor(s1, m, 32);
            s2 += __shfl_xor(s2, m, 32);
            s3 += __shfl_xor(s3, m, 32);
          }
          float sel = (jOwn == 0) ? s0 : (jOwn == 1) ? s1 : (jOwn == 2) ? s2 : s3;
          if (t == tOwn) {
            sOwn = sel;
            eOwn = ebase + jOwn;  // ebase already includes grp*4
          }
          v0 = n0; v1 = n1; v2 = n2; v3 = n3;
        }
      }
      if (eOwn >= 0 && eOwn < E) {  // 64-lane parallel epilogue
        float tt = 1.f - 2.f / (__expf(2.f * sOwn) + 1.f);  // tanh
        int sv = src[eOwn], dv = dst[eOwn];
        float val = fmaxf(eh[sv] + et[dv] + tt, 0.f);  // relu
        float ev = __expf(val);
        int slot = atomicAdd(ct + dv, 1);
        if (slot < BCAP) {
          int sl = sv - (dv / npg) * npg;
          bn[(size_t)dv * BCAP + slot] = make_float2(ev, __int_as_float(sl));
        }
      }
    }
  }
}

// ---------------- K5a: ft[v] = (sum_e ev_e * h[src_e]) / sum_e ev_e ----------------
__global__ __launch_bounds__(256) void ft_kernel(
    const float* __restrict__ h, const float2* __restrict__ bins,
    const int* __restrict__ cnt, float* __restrict__ ft, int N, int npg) {
  int wid = (blockIdx.x * blockDim.x + threadIdx.x) >> 6;
  int grp = (threadIdx.x >> 5) & 1;
  int gl = threadIdx.x & 31;
  int v = wid * 2 + grp;
  if (v >= N) return;
  int deg = min(cnt[v], BCAP);
  size_t hbase = (size_t)(v / npg) * npg * 32;  // graph slab, float4 units
  const float4* h4 = (const float4*)h;
  const float2* bp = bins + (size_t)v * BCAP;
  float4 acc = make_float4(0.f, 0.f, 0.f, 0.f);
  float dsum = 0.f;
  for (int base = 0; base < deg; base += 32) {
    int i = base + gl;
    float av = 0.f;
    int sv = 0;
    if (i < deg) {
      float2 p = bp[i];
      av = p.x;
      sv = __float_as_int(p.y);
      dsum += av;
    }
    int c = min(32, deg - base);
    int c8 = (c + 7) & ~7;
    for (int j = 0; j < c8; j += 8) {
#pragma unroll
      for (int jj = 0; jj < 8; ++jj) {
        float a = __shfl(av, j + jj, 32);
        int s = __shfl(sv, j + jj, 32);
        float4 hv = h4[hbase + (size_t)s * 32 + gl];
        acc.x += a * hv.x;
        acc.y += a * hv.y;
        acc.z += a * hv.z;
        acc.w += a * hv.w;
      }
    }
  }
#pragma unroll
  for (int mm = 16; mm > 0; mm >>= 1) dsum += __shfl_xor(dsum, mm, 32);
  float inv = (deg > 0) ? 1.f / dsum : 0.f;
  acc.x *= inv; acc.y *= inv; acc.z *= inv; acc.w *= inv;
  ((float4*)ft)[(size_t)v * 32 + gl] = acc;
}

// ---------------- K5b: z = ft @ Wfc^T + b -> normalize -> softmax -> S ----------------
__global__ __launch_bounds__(256) void assign_kernel(const float* __restrict__ ft,
                                                     const float* __restrict__ Wfc,
                                                     const float* __restrict__ bfc,
                                                     float* __restrict__ S, int N) {
  __shared__ float Wt[128 * 128];
  __shared__ float fsh[4][256];
  int t = threadIdx.x;
  for (int i = t; i < 128 * 128; i += 256) {
    int d = i >> 7, k = i & 127;
    Wt[i] = Wfc[k * 128 + d];
  }
  __syncthreads();
  int w = t >> 6, lane = t & 63;
  float b0 = bfc[2 * lane], b1 = bfc[2 * lane + 1];
  int totalWaves = gridDim.x * 4;
  int pairs = N >> 1;
  int iters = (pairs + totalWaves - 1) / totalWaves;
  for (int it = 0; it < iters; ++it) {
    int pr = blockIdx.x * 4 + w + it * totalWaves;
    bool active = (pr < pairs);
    int va = 2 * pr, vb = 2 * pr + 1;
    if (active) {
      float2 fa = *(const float2*)(ft + (size_t)va * 128 + 2 * lane);
      float2 fb = *(const float2*)(ft + (size_t)vb * 128 + 2 * lane);
      *(float2*)(&fsh[w][2 * lane]) = fa;
      *(float2*)(&fsh[w][128 + 2 * lane]) = fb;
    }
    __syncthreads();
    if (active) {
      float za0 = b0, za1 = b1, zb0 = b0, zb1 = b1;
#pragma unroll 4
      for (int d = 0; d < 128; ++d) {
        float fda = fsh[w][d];
        float fdb = fsh[w][128 + d];
        float2 wv = *(const float2*)(Wt + d * 128 + 2 * lane);
        za0 += fda * wv.x;
        za1 += fda * wv.y;
        zb0 += fdb * wv.x;
        zb1 += fdb * wv.y;
      }
      float nra = sqrtf(wave_reduce_sum(za0 * za0 + za1 * za1));
      float nrb = sqrtf(wave_reduce_sum(zb0 * zb0 + zb1 * zb1));
      float da = fmaxf(nra, 1e-12f), db = fmaxf(nrb, 1e-12f);
      za0 /= da; za1 /= da; zb0 /= db; zb1 /= db;
      float Ma = wave_reduce_max(fmaxf(za0, za1));
      float Mb = wave_reduce_max(fmaxf(zb0, zb1));
      float ea0 = __expf(za0 - Ma), ea1 = __expf(za1 - Ma);
      float eb0 = __expf(zb0 - Mb), eb1 = __expf(zb1 - Mb);
      float sa = wave_reduce_sum(ea0 + ea1);
      float sb = wave_reduce_sum(eb0 + eb1);
      *(float2*)(S + (size_t)va * 128 + 2 * lane) = make_float2(ea0 / sa, ea1 / sa);
      *(float2*)(S + (size_t)vb * 128 + 2 * lane) = make_float2(eb0 / sb, eb1 / sb);
    }
    __syncthreads();
  }
}

// ---------------- K6: P[v] = sum_e S[src_e] (bins, weight 1) ----------------
__global__ __launch_bounds__(256) void pmat_kernel(
    const float* __restrict__ S, const float2* __restrict__ bins,
    const int* __restrict__ cnt, float* __restrict__ P, int N, int npg) {
  int wid = (blockIdx.x * blockDim.x + threadIdx.x) >> 6;
  int grp = (threadIdx.x >> 5) & 1;
  int gl = threadIdx.x & 31;
  int v = wid * 2 + grp;
  if (v >= N) return;
  int deg = min(cnt[v], BCAP);
  size_t sbase = (size_t)(v / npg) * npg * 32;
  const float4* S4 = (const float4*)S;
  const float2* bp = bins + (size_t)v * BCAP;
  float4 acc = make_float4(0.f, 0.f, 0.f, 0.f);
  for (int base = 0; base < deg; base += 32) {
    int i = base + gl;
    float av = 0.f;
    int sv = 0;
    if (i < deg) {
      av = 1.f;
      sv = __float_as_int(bp[i].y);
    }
    int c = min(32, deg - base);
    int c8 = (c + 7) & ~7;
    for (int j = 0; j < c8; j += 8) {
#pragma unroll
      for (int jj = 0; jj < 8; ++jj) {
        float a = __shfl(av, j + jj, 32);
        int s = __shfl(sv, j + jj, 32);
        float4 hv = S4[sbase + (size_t)s * 32 + gl];
        acc.x += a * hv.x;
        acc.y += a * hv.y;
        acc.z += a * hv.z;
        acc.w += a * hv.w;
      }
    }
  }
  ((float4*)P)[(size_t)v * 32 + gl] = acc;
}

// ---------------- K7a: per-graph GEMM split-K partials (no atomics) ----------------
__global__ __launch_bounds__(256) void pool_gemm_part_kernel(const float* __restrict__ A,
                                                             const float* __restrict__ Bm,
                                                             float* __restrict__ part,
                                                             int npg, int kchunks) {
  int g = blockIdx.y;
  int slab = blockIdx.x;  // 8 slabs of 16 d
  int kc = blockIdx.z;
  int nper = npg / kchunks;
  int nlo = kc * nper, nhi = nlo + nper;
  int t = threadIdx.x;
  int k = t & 127;
  int dbase = slab * 16 + (t >> 7) * 8;
  float acc0 = 0.f, acc1 = 0.f, acc2 = 0.f, acc3 = 0.f;
  float acc4 = 0.f, acc5 = 0.f, acc6 = 0.f, acc7 = 0.f;
  const float* Ag = A + (size_t)g * npg * 128;
  const float* Bg = Bm + (size_t)g * npg * 128;
#pragma unroll 4
  for (int n = nlo; n < nhi; ++n) {
    float a = Ag[(size_t)n * 128 + k];
    const float* br = Bg + (size_t)n * 128 + dbase;
    float4 b0 = *(const float4*)br;
    float4 b1 = *(const float4*)(br + 4);
    acc0 += a * b0.x; acc1 += a * b0.y; acc2 += a * b0.z; acc3 += a * b0.w;
    acc4 += a * b1.x; acc5 += a * b1.y; acc6 += a * b1.z; acc7 += a * b1.w;
  }
  float* orow = part + ((size_t)kc * 32 + g) * 16384 + (size_t)k * 128 + dbase;
  orow[0] = acc0; orow[1] = acc1; orow[2] = acc2; orow[3] = acc3;
  orow[4] = acc4; orow[5] = acc5; orow[6] = acc6; orow[7] = acc7;
}

// ---------------- K7b: reduce 8 partials -> output layout ----------------
__global__ void pool_reduce_kernel(const float* __restrict__ part, float* __restrict__ out,
                                   long g_stride, int row_stride) {
  int idx = blockIdx.x * 256 + threadIdx.x;  // over 32*16384
  const int stride = 32 * 16384;
  float s = 0.f;
#pragma unroll
  for (int kc = 0; kc < 8; ++kc) s += part[idx + kc * stride];
  int g = idx >> 14;
  int rem = idx & 16383;
  int k = rem >> 7;
  int d = rem & 127;
  out[(size_t)g * g_stride + (size_t)k * row_stride + d] = s;
}

extern "C" void kernel_launch(void* const* d_in, const int* in_sizes, int n_in,
                              void* d_out, int out_size, void* d_ws, size_t ws_size,
                              hipStream_t stream) {
  const float* h      = (const float*)d_in[0];
  const float* r      = (const float*)d_in[1];
  const float* W_head = (const float*)d_in[2];
  const float* W_tail = (const float*)d_in[3];
  const float* W_rel  = (const float*)d_in[4];
  const float* W_fc   = (const float*)d_in[5];
  const float* b_fc   = (const float*)d_in[6];
  const int*   src    = (const int*)d_in[7];
  const int*   dst    = (const int*)d_in[8];

  const int B = 32;
  const int D = 128;
  const int N = in_sizes[0] / D;  // 32768
  const int E = in_sizes[7];      // 1048576
  const int npg = N / B;          // 1024

  char* wsb = (char*)d_ws;
  size_t off = 0;
  auto alloc = [&](size_t bytes) -> void* {
    void* p = wsb + off;
    off = (off + bytes + 255) & ~(size_t)255;
    return p;
  };
  float*  eh    = (float*)alloc((size_t)N * 4);
  float*  et    = (float*)alloc((size_t)N * 4);
  int*    cnt   = (int*)alloc((size_t)N * 4);
  int*    cnt0  = (int*)alloc((size_t)N * 4);
  float2* bins  = (float2*)alloc((size_t)N * BCAP * 8);  // 33.5 MB
  float2* bins0 = (float2*)alloc((size_t)N * BCAP * 8);  // 33.5 MB scratch (probe)
  float*  ft    = (float*)alloc((size_t)N * 128 * 4);
  float*  S     = (float*)alloc((size_t)N * 128 * 4);
  float*  P     = (float*)alloc((size_t)N * 128 * 4);
  float*  part  = (float*)alloc((size_t)8 * 32 * 16384 * 4);  // 16 MB
  (void)ws_size;

  zero_kernel<<<2048, 256, 0, stream>>>((float4*)d_out, out_size / 4);
  init_counters_kernel<<<(N + 255) / 256, 256, 0, stream>>>(cnt, cnt0, N);

  node_gate_kernel<<<N / 4, 256, 0, stream>>>(h, W_head, W_tail, eh, et, N);
  {
    int blocks = 2048;
    int nwaves = blocks * 4;
    edge_logit_kernel<<<blocks, 256, 0, stream>>>(r, W_rel, eh, et, src, dst,
                                                  cnt0, bins0, cnt, bins,
                                                  E, nwaves, npg);
  }
  ft_kernel<<<N / 8, 256, 0, stream>>>(h, bins, cnt, ft, N, npg);
  assign_kernel<<<512, 256, 0, stream>>>(ft, W_fc, b_fc, S, N);
  pmat_kernel<<<N / 8, 256, 0, stream>>>(S, bins, cnt, P, N, npg);

  float* out_f = (float*)d_out;
  const long adj_elems = (long)(B * 128) * (B * 128);
  // h_pool = S^T h
  pool_gemm_part_kernel<<<dim3(8, B, 8), 256, 0, stream>>>(S, h, part, npg, 8);
  pool_reduce_kernel<<<(32 * 16384) / 256, 256, 0, stream>>>(part, out_f + adj_elems,
                                                             (long)128 * 128, 128);
  // adj blocks = P^T S
  pool_gemm_part_kernel<<<dim3(8, B, 8), 256, 0, stream>>>(P, S, part, npg, 8);
  pool_reduce_kernel<<<(32 * 16384) / 256, 256, 0, stream>>>(part, out_f,
                                                             (long)(128 * (B * 128) + 128),
                                                             B * 128);
}

// Round 17
// 462.546 us; speedup vs baseline: 1.2263x; 1.2263x over previous
//
#include <hip/hip_runtime.h>
#include <hip/hip_bf16.h>
#include <math.h>

#define BCAP 128  // per-node edge bin capacity (mean deg 32, P(>128) ~ 0)

__device__ __forceinline__ float wave_reduce_sum(float v) {
#pragma unroll
  for (int m = 32; m > 0; m >>= 1) v += __shfl_xor(v, m, 64);
  return v;
}
__device__ __forceinline__ float wave_reduce_max(float v) {
#pragma unroll
  for (int m = 32; m > 0; m >>= 1) v = fmaxf(v, __shfl_xor(v, m, 64));
  return v;
}

// ---------------- K0: zero out[] AND cnt[] in one dispatch ----------------
__global__ void zero_kernel(float4* __restrict__ out4, int n4_out,
                            float4* __restrict__ cnt4, int n4_cnt) {
  int i = blockIdx.x * blockDim.x + threadIdx.x;
  int stride = gridDim.x * blockDim.x;
  float4 z = make_float4(0.f, 0.f, 0.f, 0.f);
  int total = n4_out + n4_cnt;
  for (; i < total; i += stride) {
    if (i < n4_out) out4[i] = z;
    else cnt4[i - n4_out] = z;
  }
}

// ---------------- K1: per-node head/tail gates ----------------
__global__ void node_gate_kernel(const float* __restrict__ h,
                                 const float* __restrict__ Wh,
                                 const float* __restrict__ Wt,
                                 float* __restrict__ eh, float* __restrict__ et,
                                 int N) {
  int v = (blockIdx.x * blockDim.x + threadIdx.x) >> 6;
  int lane = threadIdx.x & 63;
  if (v >= N) return;
  float2 hv = *(const float2*)(h + (size_t)v * 128 + 2 * lane);
  float2 wh = *(const float2*)(Wh + 2 * lane);
  float2 wt = *(const float2*)(Wt + 2 * lane);
  float ah = hv.x * wh.x + hv.y * wh.y;
  float at = hv.x * wt.x + hv.y * wt.y;
  ah = wave_reduce_sum(ah);
  at = wave_reduce_sum(at);
  if (lane == 0) {
    eh[v] = tanhf(ah);
    et[v] = tanhf(at);
  }
}

// ---------------- K2: fused edge kernel, burst-collected epilogue ----------------
// 2-deep pipelined r stream; every 8 iters, 64-lane parallel epilogue appends
// {exp(relu(logit)), src_local} into per-dst bins. ebase already includes
// grp*4 (eOwn = ebase + jOwn). No segment-max: logit in [0,3), exp <= 20.1.
__global__ __launch_bounds__(256) void edge_logit_kernel(
    const float* __restrict__ r, const float* __restrict__ Wr,
    const float* __restrict__ eh, const float* __restrict__ et,
    const int* __restrict__ src, const int* __restrict__ dst,
    int* __restrict__ cnt, float2* __restrict__ bins,
    int E, int nwaves, int npg) {
  int wid = (blockIdx.x * blockDim.x + threadIdx.x) >> 6;
  int grp = (threadIdx.x >> 5) & 1;
  int gl = threadIdx.x & 31;
  int tOwn = gl >> 2, jOwn = gl & 3;
  const float4* r4 = (const float4*)r;
  float4 w4 = ((const float4*)Wr)[gl];
  int step = nwaves * 8;
  int e0 = wid * 8 + grp * 4;
  if (e0 >= E) return;
  size_t rb = (size_t)e0 * 32 + gl;
  float4 v0 = r4[rb];
  float4 v1 = r4[rb + 32];
  float4 v2 = r4[rb + 64];
  float4 v3 = r4[rb + 96];
  for (int bb = e0; bb < E; bb += step * 8) {
    float sOwn = 0.f;
    int eOwn = -1;
#pragma unroll
    for (int t = 0; t < 8; ++t) {
      int ebase = bb + t * step;
      if (ebase < E) {
        int enext = ebase + step;
        float4 n0 = make_float4(0.f, 0.f, 0.f, 0.f), n1 = n0, n2 = n0, n3 = n0;
        if (enext < E) {
          size_t nb = (size_t)enext * 32 + gl;
          n0 = r4[nb];
          n1 = r4[nb + 32];
          n2 = r4[nb + 64];
          n3 = r4[nb + 96];
        }
        float s0 = v0.x * w4.x + v0.y * w4.y + v0.z * w4.z + v0.w * w4.w;
        float s1 = v1.x * w4.x + v1.y * w4.y + v1.z * w4.z + v1.w * w4.w;
        float s2 = v2.x * w4.x + v2.y * w4.y + v2.z * w4.z + v2.w * w4.w;
        float s3 = v3.x * w4.x + v3.y * w4.y + v3.z * w4.z + v3.w * w4.w;
#pragma unroll
        for (int m = 16; m > 0; m >>= 1) {
          s0 += __shfl_xor(s0, m, 32);
          s1 += __shfl_xor(s1, m, 32);
          s2 += __shfl_xor(s2, m, 32);
          s3 += __shfl_xor(s3, m, 32);
        }
        float sel = (jOwn == 0) ? s0 : (jOwn == 1) ? s1 : (jOwn == 2) ? s2 : s3;
        if (t == tOwn) {
          sOwn = sel;
          eOwn = ebase + jOwn;
        }
        v0 = n0; v1 = n1; v2 = n2; v3 = n3;
      }
    }
    if (eOwn >= 0 && eOwn < E) {  // 64-lane parallel epilogue
      float tt = 1.f - 2.f / (__expf(2.f * sOwn) + 1.f);  // tanh
      int sv = src[eOwn], dv = dst[eOwn];
      float val = fmaxf(eh[sv] + et[dv] + tt, 0.f);  // relu
      float ev = __expf(val);
      int slot = atomicAdd(cnt + dv, 1);
      if (slot < BCAP) {
        int sl = sv - (dv / npg) * npg;
        bins[(size_t)dv * BCAP + slot] = make_float2(ev, __int_as_float(sl));
      }
    }
  }
}

// ---------------- K5a: ft[v] = (sum_e ev_e * h[src_e]) / sum_e ev_e ----------------
__global__ __launch_bounds__(256) void ft_kernel(
    const float* __restrict__ h, const float2* __restrict__ bins,
    const int* __restrict__ cnt, float* __restrict__ ft, int N, int npg) {
  int wid = (blockIdx.x * blockDim.x + threadIdx.x) >> 6;
  int grp = (threadIdx.x >> 5) & 1;
  int gl = threadIdx.x & 31;
  int v = wid * 2 + grp;
  if (v >= N) return;
  int deg = min(cnt[v], BCAP);
  size_t hbase = (size_t)(v / npg) * npg * 32;  // graph slab, float4 units
  const float4* h4 = (const float4*)h;
  const float2* bp = bins + (size_t)v * BCAP;
  float4 acc = make_float4(0.f, 0.f, 0.f, 0.f);
  float dsum = 0.f;
  for (int base = 0; base < deg; base += 32) {
    int i = base + gl;
    float av = 0.f;
    int sv = 0;
    if (i < deg) {
      float2 p = bp[i];
      av = p.x;
      sv = __float_as_int(p.y);
      dsum += av;
    }
    int c = min(32, deg - base);
    int c8 = (c + 7) & ~7;
    for (int j = 0; j < c8; j += 8) {
#pragma unroll
      for (int jj = 0; jj < 8; ++jj) {
        float a = __shfl(av, j + jj, 32);
        int s = __shfl(sv, j + jj, 32);
        float4 hv = h4[hbase + (size_t)s * 32 + gl];
        acc.x += a * hv.x;
        acc.y += a * hv.y;
        acc.z += a * hv.z;
        acc.w += a * hv.w;
      }
    }
  }
#pragma unroll
  for (int mm = 16; mm > 0; mm >>= 1) dsum += __shfl_xor(dsum, mm, 32);
  float inv = (deg > 0) ? 1.f / dsum : 0.f;
  acc.x *= inv; acc.y *= inv; acc.z *= inv; acc.w *= inv;
  ((float4*)ft)[(size_t)v * 32 + gl] = acc;
}

// ---------------- K5b: z = ft @ Wfc^T + b -> normalize -> softmax -> S ----------------
__global__ __launch_bounds__(256) void assign_kernel(const float* __restrict__ ft,
                                                     const float* __restrict__ Wfc,
                                                     const float* __restrict__ bfc,
                                                     float* __restrict__ S, int N) {
  __shared__ float Wt[128 * 128];
  __shared__ float fsh[4][256];
  int t = threadIdx.x;
  for (int i = t; i < 128 * 128; i += 256) {
    int d = i >> 7, k = i & 127;
    Wt[i] = Wfc[k * 128 + d];
  }
  __syncthreads();
  int w = t >> 6, lane = t & 63;
  float b0 = bfc[2 * lane], b1 = bfc[2 * lane + 1];
  int totalWaves = gridDim.x * 4;
  int pairs = N >> 1;
  int iters = (pairs + totalWaves - 1) / totalWaves;
  for (int it = 0; it < iters; ++it) {
    int pr = blockIdx.x * 4 + w + it * totalWaves;
    bool active = (pr < pairs);
    int va = 2 * pr, vb = 2 * pr + 1;
    if (active) {
      float2 fa = *(const float2*)(ft + (size_t)va * 128 + 2 * lane);
      float2 fb = *(const float2*)(ft + (size_t)vb * 128 + 2 * lane);
      *(float2*)(&fsh[w][2 * lane]) = fa;
      *(float2*)(&fsh[w][128 + 2 * lane]) = fb;
    }
    __syncthreads();
    if (active) {
      float za0 = b0, za1 = b1, zb0 = b0, zb1 = b1;
#pragma unroll 4
      for (int d = 0; d < 128; ++d) {
        float fda = fsh[w][d];
        float fdb = fsh[w][128 + d];
        float2 wv = *(const float2*)(Wt + d * 128 + 2 * lane);
        za0 += fda * wv.x;
        za1 += fda * wv.y;
        zb0 += fdb * wv.x;
        zb1 += fdb * wv.y;
      }
      float nra = sqrtf(wave_reduce_sum(za0 * za0 + za1 * za1));
      float nrb = sqrtf(wave_reduce_sum(zb0 * zb0 + zb1 * zb1));
      float da = fmaxf(nra, 1e-12f), db = fmaxf(nrb, 1e-12f);
      za0 /= da; za1 /= da; zb0 /= db; zb1 /= db;
      float Ma = wave_reduce_max(fmaxf(za0, za1));
      float Mb = wave_reduce_max(fmaxf(zb0, zb1));
      float ea0 = __expf(za0 - Ma), ea1 = __expf(za1 - Ma);
      float eb0 = __expf(zb0 - Mb), eb1 = __expf(zb1 - Mb);
      float sa = wave_reduce_sum(ea0 + ea1);
      float sb = wave_reduce_sum(eb0 + eb1);
      *(float2*)(S + (size_t)va * 128 + 2 * lane) = make_float2(ea0 / sa, ea1 / sa);
      *(float2*)(S + (size_t)vb * 128 + 2 * lane) = make_float2(eb0 / sb, eb1 / sb);
    }
    __syncthreads();
  }
}

// ---------------- K6: P[v] = sum_e S[src_e] (bins, weight 1) ----------------
__global__ __launch_bounds__(256) void pmat_kernel(
    const float* __restrict__ S, const float2* __restrict__ bins,
    const int* __restrict__ cnt, float* __restrict__ P, int N, int npg) {
  int wid = (blockIdx.x * blockDim.x + threadIdx.x) >> 6;
  int grp = (threadIdx.x >> 5) & 1;
  int gl = threadIdx.x & 31;
  int v = wid * 2 + grp;
  if (v >= N) return;
  int deg = min(cnt[v], BCAP);
  size_t sbase = (size_t)(v / npg) * npg * 32;
  const float4* S4 = (const float4*)S;
  const float2* bp = bins + (size_t)v * BCAP;
  float4 acc = make_float4(0.f, 0.f, 0.f, 0.f);
  for (int base = 0; base < deg; base += 32) {
    int i = base + gl;
    float av = 0.f;
    int sv = 0;
    if (i < deg) {
      av = 1.f;
      sv = __float_as_int(bp[i].y);
    }
    int c = min(32, deg - base);
    int c8 = (c + 7) & ~7;
    for (int j = 0; j < c8; j += 8) {
#pragma unroll
      for (int jj = 0; jj < 8; ++jj) {
        float a = __shfl(av, j + jj, 32);
        int s = __shfl(sv, j + jj, 32);
        float4 hv = S4[sbase + (size_t)s * 32 + gl];
        acc.x += a * hv.x;
        acc.y += a * hv.y;
        acc.z += a * hv.z;
        acc.w += a * hv.w;
      }
    }
  }
  ((float4*)P)[(size_t)v * 32 + gl] = acc;
}

// ---------------- K7a: BOTH pool GEMMs, split-K x8, one dispatch ----------------
// z in [0,16): z<8 -> chunk z of S^T h; z>=8 -> chunk z-8 of P^T S.
__global__ __launch_bounds__(256) void pool_gemm_part_kernel(
    const float* __restrict__ S, const float* __restrict__ h,
    const float* __restrict__ P, float* __restrict__ part, int npg) {
  int g = blockIdx.y;
  int slab = blockIdx.x;  // 8 slabs of 16 d
  int z = blockIdx.z;
  const float* A = (z < 8) ? S : P;
  const float* Bm = (z < 8) ? h : S;
  int kc = z & 7;
  int nper = npg / 8;
  int nlo = kc * nper, nhi = nlo + nper;
  int t = threadIdx.x;
  int k = t & 127;
  int dbase = slab * 16 + (t >> 7) * 8;
  float acc0 = 0.f, acc1 = 0.f, acc2 = 0.f, acc3 = 0.f;
  float acc4 = 0.f, acc5 = 0.f, acc6 = 0.f, acc7 = 0.f;
  const float* Ag = A + (size_t)g * npg * 128;
  const float* Bg = Bm + (size_t)g * npg * 128;
#pragma unroll 4
  for (int n = nlo; n < nhi; ++n) {
    float a = Ag[(size_t)n * 128 + k];
    const float* br = Bg + (size_t)n * 128 + dbase;
    float4 b0 = *(const float4*)br;
    float4 b1 = *(const float4*)(br + 4);
    acc0 += a * b0.x; acc1 += a * b0.y; acc2 += a * b0.z; acc3 += a * b0.w;
    acc4 += a * b1.x; acc5 += a * b1.y; acc6 += a * b1.z; acc7 += a * b1.w;
  }
  float* orow = part + ((size_t)z * 32 + g) * 16384 + (size_t)k * 128 + dbase;
  orow[0] = acc0; orow[1] = acc1; orow[2] = acc2; orow[3] = acc3;
  orow[4] = acc4; orow[5] = acc5; orow[6] = acc6; orow[7] = acc7;
}

// ---------------- K7b: reduce both partial sets -> output, one dispatch ----------------
// First half of grid: h_pool (chunks 0..7); second half: adj (chunks 8..15).
__global__ void pool_reduce_kernel(const float* __restrict__ part, float* __restrict__ out,
                                   long adj_elems) {
  const int per = 32 * 16384;
  int idx = blockIdx.x * 256 + threadIdx.x;
  int half = (idx >= per);
  int li = idx - half * per;
  const float* pb = part + (size_t)half * 8 * per;
  float s = 0.f;
#pragma unroll
  for (int kc = 0; kc < 8; ++kc) s += pb[li + kc * per];
  int g = li >> 14;
  int rem = li & 16383;
  int k = rem >> 7;
  int d = rem & 127;
  if (half == 0) {  // h_pool: [B][128][128] after adj
    out[adj_elems + (size_t)g * 16384 + (size_t)k * 128 + d] = s;
  } else {  // adj diag blocks: out[(g*128+k)*4096 + g*128 + d]
    out[(size_t)g * (128L * 4096 + 128) + (size_t)k * 4096 + d] = s;
  }
}

extern "C" void kernel_launch(void* const* d_in, const int* in_sizes, int n_in,
                              void* d_out, int out_size, void* d_ws, size_t ws_size,
                              hipStream_t stream) {
  const float* h      = (const float*)d_in[0];
  const float* r      = (const float*)d_in[1];
  const float* W_head = (const float*)d_in[2];
  const float* W_tail = (const float*)d_in[3];
  const float* W_rel  = (const float*)d_in[4];
  const float* W_fc   = (const float*)d_in[5];
  const float* b_fc   = (const float*)d_in[6];
  const int*   src    = (const int*)d_in[7];
  const int*   dst    = (const int*)d_in[8];

  const int B = 32;
  const int D = 128;
  const int N = in_sizes[0] / D;  // 32768
  const int E = in_sizes[7];      // 1048576
  const int npg = N / B;          // 1024

  char* wsb = (char*)d_ws;
  size_t off = 0;
  auto alloc = [&](size_t bytes) -> void* {
    void* p = wsb + off;
    off = (off + bytes + 255) & ~(size_t)255;
    return p;
  };
  float*  eh   = (float*)alloc((size_t)N * 4);
  float*  et   = (float*)alloc((size_t)N * 4);
  int*    cnt  = (int*)alloc((size_t)N * 4);
  float2* bins = (float2*)alloc((size_t)N * BCAP * 8);         // 33.5 MB
  float*  ft   = (float*)alloc((size_t)N * 128 * 4);
  float*  S    = (float*)alloc((size_t)N * 128 * 4);
  float*  P    = (float*)alloc((size_t)N * 128 * 4);
  float*  part = (float*)alloc((size_t)16 * 32 * 16384 * 4);   // 32 MB
  (void)ws_size;

  // zero out[] + cnt[] in one dispatch
  zero_kernel<<<2048, 256, 0, stream>>>((float4*)d_out, out_size / 4,
                                        (float4*)cnt, N / 4);

  node_gate_kernel<<<N / 4, 256, 0, stream>>>(h, W_head, W_tail, eh, et, N);
  {
    int blocks = 4096;  // 16 blocks/CU: extra waves cover epilogue stalls
    int nwaves = blocks * 4;
    edge_logit_kernel<<<blocks, 256, 0, stream>>>(r, W_rel, eh, et, src, dst,
                                                  cnt, bins, E, nwaves, npg);
  }
  ft_kernel<<<N / 8, 256, 0, stream>>>(h, bins, cnt, ft, N, npg);
  assign_kernel<<<512, 256, 0, stream>>>(ft, W_fc, b_fc, S, N);
  pmat_kernel<<<N / 8, 256, 0, stream>>>(S, bins, cnt, P, N, npg);

  float* out_f = (float*)d_out;
  const long adj_elems = (long)(B * 128) * (B * 128);
  // both pool GEMMs (split-K x8 each) in one dispatch
  pool_gemm_part_kernel<<<dim3(8, B, 16), 256, 0, stream>>>(S, h, P, part, npg);
  // both reductions in one dispatch
  pool_reduce_kernel<<<(2 * 32 * 16384) / 256, 256, 0, stream>>>(part, out_f, adj_elems);
}

// Round 18
// 451.211 us; speedup vs baseline: 1.2572x; 1.0251x over previous
//
#include <hip/hip_runtime.h>
#include <hip/hip_bf16.h>
#include <math.h>

#define BCAP 128  // per-node edge bin capacity (mean deg 32, P(>128) ~ 0)

__device__ __forceinline__ float wave_reduce_sum(float v) {
#pragma unroll
  for (int m = 32; m > 0; m >>= 1) v += __shfl_xor(v, m, 64);
  return v;
}
__device__ __forceinline__ float wave_reduce_max(float v) {
#pragma unroll
  for (int m = 32; m > 0; m >>= 1) v = fmaxf(v, __shfl_xor(v, m, 64));
  return v;
}

// ---------------- K0: zero out[] AND cnt[] in one dispatch ----------------
__global__ void zero_kernel(float4* __restrict__ out4, int n4_out,
                            float4* __restrict__ cnt4, int n4_cnt) {
  int i = blockIdx.x * blockDim.x + threadIdx.x;
  int stride = gridDim.x * blockDim.x;
  float4 z = make_float4(0.f, 0.f, 0.f, 0.f);
  int total = n4_out + n4_cnt;
  for (; i < total; i += stride) {
    if (i < n4_out) out4[i] = z;
    else cnt4[i - n4_out] = z;
  }
}

// ---------------- K1: per-node head/tail gates ----------------
__global__ void node_gate_kernel(const float* __restrict__ h,
                                 const float* __restrict__ Wh,
                                 const float* __restrict__ Wt,
                                 float* __restrict__ eh, float* __restrict__ et,
                                 int N) {
  int v = (blockIdx.x * blockDim.x + threadIdx.x) >> 6;
  int lane = threadIdx.x & 63;
  if (v >= N) return;
  float2 hv = *(const float2*)(h + (size_t)v * 128 + 2 * lane);
  float2 wh = *(const float2*)(Wh + 2 * lane);
  float2 wt = *(const float2*)(Wt + 2 * lane);
  float ah = hv.x * wh.x + hv.y * wh.y;
  float at = hv.x * wt.x + hv.y * wt.y;
  ah = wave_reduce_sum(ah);
  at = wave_reduce_sum(at);
  if (lane == 0) {
    eh[v] = tanhf(ah);
    et[v] = tanhf(at);
  }
}

// ---------------- K2: fused edge kernel, burst-collected epilogue ----------------
// 2-deep pipelined r stream; every 8 iters, 64-lane parallel epilogue appends
// {exp(relu(logit)), src_local} into per-dst bins. ebase already includes
// grp*4 (eOwn = ebase + jOwn). No segment-max: logit in [0,3), exp <= 20.1.
// blocks=2048 (R15-verified; 4096 regressed in R17).
__global__ __launch_bounds__(256) void edge_logit_kernel(
    const float* __restrict__ r, const float* __restrict__ Wr,
    const float* __restrict__ eh, const float* __restrict__ et,
    const int* __restrict__ src, const int* __restrict__ dst,
    int* __restrict__ cnt, float2* __restrict__ bins,
    int E, int nwaves, int npg) {
  int wid = (blockIdx.x * blockDim.x + threadIdx.x) >> 6;
  int grp = (threadIdx.x >> 5) & 1;
  int gl = threadIdx.x & 31;
  int tOwn = gl >> 2, jOwn = gl & 3;
  const float4* r4 = (const float4*)r;
  float4 w4 = ((const float4*)Wr)[gl];
  int step = nwaves * 8;
  int e0 = wid * 8 + grp * 4;
  if (e0 >= E) return;
  size_t rb = (size_t)e0 * 32 + gl;
  float4 v0 = r4[rb];
  float4 v1 = r4[rb + 32];
  float4 v2 = r4[rb + 64];
  float4 v3 = r4[rb + 96];
  for (int bb = e0; bb < E; bb += step * 8) {
    float sOwn = 0.f;
    int eOwn = -1;
#pragma unroll
    for (int t = 0; t < 8; ++t) {
      int ebase = bb + t * step;
      if (ebase < E) {
        int enext = ebase + step;
        float4 n0 = make_float4(0.f, 0.f, 0.f, 0.f), n1 = n0, n2 = n0, n3 = n0;
        if (enext < E) {
          size_t nb = (size_t)enext * 32 + gl;
          n0 = r4[nb];
          n1 = r4[nb + 32];
          n2 = r4[nb + 64];
          n3 = r4[nb + 96];
        }
        float s0 = v0.x * w4.x + v0.y * w4.y + v0.z * w4.z + v0.w * w4.w;
        float s1 = v1.x * w4.x + v1.y * w4.y + v1.z * w4.z + v1.w * w4.w;
        float s2 = v2.x * w4.x + v2.y * w4.y + v2.z * w4.z + v2.w * w4.w;
        float s3 = v3.x * w4.x + v3.y * w4.y + v3.z * w4.z + v3.w * w4.w;
#pragma unroll
        for (int m = 16; m > 0; m >>= 1) {
          s0 += __shfl_xor(s0, m, 32);
          s1 += __shfl_xor(s1, m, 32);
          s2 += __shfl_xor(s2, m, 32);
          s3 += __shfl_xor(s3, m, 32);
        }
        float sel = (jOwn == 0) ? s0 : (jOwn == 1) ? s1 : (jOwn == 2) ? s2 : s3;
        if (t == tOwn) {
          sOwn = sel;
          eOwn = ebase + jOwn;
        }
        v0 = n0; v1 = n1; v2 = n2; v3 = n3;
      }
    }
    if (eOwn >= 0 && eOwn < E) {  // 64-lane parallel epilogue
      float tt = 1.f - 2.f / (__expf(2.f * sOwn) + 1.f);  // tanh
      int sv = src[eOwn], dv = dst[eOwn];
      float val = fmaxf(eh[sv] + et[dv] + tt, 0.f);  // relu
      float ev = __expf(val);
      int slot = atomicAdd(cnt + dv, 1);
      if (slot < BCAP) {
        int sl = sv - (dv / npg) * npg;
        bins[(size_t)dv * BCAP + slot] = make_float2(ev, __int_as_float(sl));
      }
    }
  }
}

// ---------------- K5a: ft[v] = (sum_e ev_e * h[src_e]) / sum_e ev_e ----------------
__global__ __launch_bounds__(256) void ft_kernel(
    const float* __restrict__ h, const float2* __restrict__ bins,
    const int* __restrict__ cnt, float* __restrict__ ft, int N, int npg) {
  int wid = (blockIdx.x * blockDim.x + threadIdx.x) >> 6;
  int grp = (threadIdx.x >> 5) & 1;
  int gl = threadIdx.x & 31;
  int v = wid * 2 + grp;
  if (v >= N) return;
  int deg = min(cnt[v], BCAP);
  size_t hbase = (size_t)(v / npg) * npg * 32;  // graph slab, float4 units
  const float4* h4 = (const float4*)h;
  const float2* bp = bins + (size_t)v * BCAP;
  float4 acc = make_float4(0.f, 0.f, 0.f, 0.f);
  float dsum = 0.f;
  for (int base = 0; base < deg; base += 32) {
    int i = base + gl;
    float av = 0.f;
    int sv = 0;
    if (i < deg) {
      float2 p = bp[i];
      av = p.x;
      sv = __float_as_int(p.y);
      dsum += av;
    }
    int c = min(32, deg - base);
    int c8 = (c + 7) & ~7;
    for (int j = 0; j < c8; j += 8) {
#pragma unroll
      for (int jj = 0; jj < 8; ++jj) {
        float a = __shfl(av, j + jj, 32);
        int s = __shfl(sv, j + jj, 32);
        float4 hv = h4[hbase + (size_t)s * 32 + gl];
        acc.x += a * hv.x;
        acc.y += a * hv.y;
        acc.z += a * hv.z;
        acc.w += a * hv.w;
      }
    }
  }
#pragma unroll
  for (int mm = 16; mm > 0; mm >>= 1) dsum += __shfl_xor(dsum, mm, 32);
  float inv = (deg > 0) ? 1.f / dsum : 0.f;
  acc.x *= inv; acc.y *= inv; acc.z *= inv; acc.w *= inv;
  ((float4*)ft)[(size_t)v * 32 + gl] = acc;
}

// ---------------- K5b: z = ft @ Wfc^T + b -> normalize -> softmax -> S ----------------
__global__ __launch_bounds__(256) void assign_kernel(const float* __restrict__ ft,
                                                     const float* __restrict__ Wfc,
                                                     const float* __restrict__ bfc,
                                                     float* __restrict__ S, int N) {
  __shared__ float Wt[128 * 128];
  __shared__ float fsh[4][256];
  int t = threadIdx.x;
  for (int i = t; i < 128 * 128; i += 256) {
    int d = i >> 7, k = i & 127;
    Wt[i] = Wfc[k * 128 + d];
  }
  __syncthreads();
  int w = t >> 6, lane = t & 63;
  float b0 = bfc[2 * lane], b1 = bfc[2 * lane + 1];
  int totalWaves = gridDim.x * 4;
  int pairs = N >> 1;
  int iters = (pairs + totalWaves - 1) / totalWaves;
  for (int it = 0; it < iters; ++it) {
    int pr = blockIdx.x * 4 + w + it * totalWaves;
    bool active = (pr < pairs);
    int va = 2 * pr, vb = 2 * pr + 1;
    if (active) {
      float2 fa = *(const float2*)(ft + (size_t)va * 128 + 2 * lane);
      float2 fb = *(const float2*)(ft + (size_t)vb * 128 + 2 * lane);
      *(float2*)(&fsh[w][2 * lane]) = fa;
      *(float2*)(&fsh[w][128 + 2 * lane]) = fb;
    }
    __syncthreads();
    if (active) {
      float za0 = b0, za1 = b1, zb0 = b0, zb1 = b1;
#pragma unroll 4
      for (int d = 0; d < 128; ++d) {
        float fda = fsh[w][d];
        float fdb = fsh[w][128 + d];
        float2 wv = *(const float2*)(Wt + d * 128 + 2 * lane);
        za0 += fda * wv.x;
        za1 += fda * wv.y;
        zb0 += fdb * wv.x;
        zb1 += fdb * wv.y;
      }
      float nra = sqrtf(wave_reduce_sum(za0 * za0 + za1 * za1));
      float nrb = sqrtf(wave_reduce_sum(zb0 * zb0 + zb1 * zb1));
      float da = fmaxf(nra, 1e-12f), db = fmaxf(nrb, 1e-12f);
      za0 /= da; za1 /= da; zb0 /= db; zb1 /= db;
      float Ma = wave_reduce_max(fmaxf(za0, za1));
      float Mb = wave_reduce_max(fmaxf(zb0, zb1));
      float ea0 = __expf(za0 - Ma), ea1 = __expf(za1 - Ma);
      float eb0 = __expf(zb0 - Mb), eb1 = __expf(zb1 - Mb);
      float sa = wave_reduce_sum(ea0 + ea1);
      float sb = wave_reduce_sum(eb0 + eb1);
      *(float2*)(S + (size_t)va * 128 + 2 * lane) = make_float2(ea0 / sa, ea1 / sa);
      *(float2*)(S + (size_t)vb * 128 + 2 * lane) = make_float2(eb0 / sb, eb1 / sb);
    }
    __syncthreads();
  }
}

// ---------------- K6: P[v] = sum_e S[src_e] (bins, weight 1) ----------------
__global__ __launch_bounds__(256) void pmat_kernel(
    const float* __restrict__ S, const float2* __restrict__ bins,
    const int* __restrict__ cnt, float* __restrict__ P, int N, int npg) {
  int wid = (blockIdx.x * blockDim.x + threadIdx.x) >> 6;
  int grp = (threadIdx.x >> 5) & 1;
  int gl = threadIdx.x & 31;
  int v = wid * 2 + grp;
  if (v >= N) return;
  int deg = min(cnt[v], BCAP);
  size_t sbase = (size_t)(v / npg) * npg * 32;
  const float4* S4 = (const float4*)S;
  const float2* bp = bins + (size_t)v * BCAP;
  float4 acc = make_float4(0.f, 0.f, 0.f, 0.f);
  for (int base = 0; base < deg; base += 32) {
    int i = base + gl;
    float av = 0.f;
    int sv = 0;
    if (i < deg) {
      av = 1.f;
      sv = __float_as_int(bp[i].y);
    }
    int c = min(32, deg - base);
    int c8 = (c + 7) & ~7;
    for (int j = 0; j < c8; j += 8) {
#pragma unroll
      for (int jj = 0; jj < 8; ++jj) {
        float a = __shfl(av, j + jj, 32);
        int s = __shfl(sv, j + jj, 32);
        float4 hv = S4[sbase + (size_t)s * 32 + gl];
        acc.x += a * hv.x;
        acc.y += a * hv.y;
        acc.z += a * hv.z;
        acc.w += a * hv.w;
      }
    }
  }
  ((float4*)P)[(size_t)v * 32 + gl] = acc;
}

// ---------------- K7a: per-graph GEMM split-K partials (no atomics) ----------------
__global__ __launch_bounds__(256) void pool_gemm_part_kernel(const float* __restrict__ A,
                                                             const float* __restrict__ Bm,
                                                             float* __restrict__ part,
                                                             int npg, int kchunks) {
  int g = blockIdx.y;
  int slab = blockIdx.x;  // 8 slabs of 16 d
  int kc = blockIdx.z;
  int nper = npg / kchunks;
  int nlo = kc * nper, nhi = nlo + nper;
  int t = threadIdx.x;
  int k = t & 127;
  int dbase = slab * 16 + (t >> 7) * 8;
  float acc0 = 0.f, acc1 = 0.f, acc2 = 0.f, acc3 = 0.f;
  float acc4 = 0.f, acc5 = 0.f, acc6 = 0.f, acc7 = 0.f;
  const float* Ag = A + (size_t)g * npg * 128;
  const float* Bg = Bm + (size_t)g * npg * 128;
#pragma unroll 4
  for (int n = nlo; n < nhi; ++n) {
    float a = Ag[(size_t)n * 128 + k];
    const float* br = Bg + (size_t)n * 128 + dbase;
    float4 b0 = *(const float4*)br;
    float4 b1 = *(const float4*)(br + 4);
    acc0 += a * b0.x; acc1 += a * b0.y; acc2 += a * b0.z; acc3 += a * b0.w;
    acc4 += a * b1.x; acc5 += a * b1.y; acc6 += a * b1.z; acc7 += a * b1.w;
  }
  float* orow = part + ((size_t)kc * 32 + g) * 16384 + (size_t)k * 128 + dbase;
  orow[0] = acc0; orow[1] = acc1; orow[2] = acc2; orow[3] = acc3;
  orow[4] = acc4; orow[5] = acc5; orow[6] = acc6; orow[7] = acc7;
}

// ---------------- K7b: reduce 8 partials -> output layout ----------------
__global__ void pool_reduce_kernel(const float* __restrict__ part, float* __restrict__ out,
                                   long g_stride, int row_stride) {
  int idx = blockIdx.x * 256 + threadIdx.x;  // over 32*16384
  const int stride = 32 * 16384;
  float s = 0.f;
#pragma unroll
  for (int kc = 0; kc < 8; ++kc) s += part[idx + kc * stride];
  int g = idx >> 14;
  int rem = idx & 16383;
  int k = rem >> 7;
  int d = rem & 127;
  out[(size_t)g * g_stride + (size_t)k * row_stride + d] = s;
}

extern "C" void kernel_launch(void* const* d_in, const int* in_sizes, int n_in,
                              void* d_out, int out_size, void* d_ws, size_t ws_size,
                              hipStream_t stream) {
  const float* h      = (const float*)d_in[0];
  const float* r      = (const float*)d_in[1];
  const float* W_head = (const float*)d_in[2];
  const float* W_tail = (const float*)d_in[3];
  const float* W_rel  = (const float*)d_in[4];
  const float* W_fc   = (const float*)d_in[5];
  const float* b_fc   = (const float*)d_in[6];
  const int*   src    = (const int*)d_in[7];
  const int*   dst    = (const int*)d_in[8];

  const int B = 32;
  const int D = 128;
  const int N = in_sizes[0] / D;  // 32768
  const int E = in_sizes[7];      // 1048576
  const int npg = N / B;          // 1024

  char* wsb = (char*)d_ws;
  size_t off = 0;
  auto alloc = [&](size_t bytes) -> void* {
    void* p = wsb + off;
    off = (off + bytes + 255) & ~(size_t)255;
    return p;
  };
  float*  eh   = (float*)alloc((size_t)N * 4);
  float*  et   = (float*)alloc((size_t)N * 4);
  int*    cnt  = (int*)alloc((size_t)N * 4);
  float2* bins = (float2*)alloc((size_t)N * BCAP * 8);         // 33.5 MB
  float*  ft   = (float*)alloc((size_t)N * 128 * 4);
  float*  S    = (float*)alloc((size_t)N * 128 * 4);
  float*  P    = (float*)alloc((size_t)N * 128 * 4);
  float*  part = (float*)alloc((size_t)8 * 32 * 16384 * 4);    // 16 MB
  (void)ws_size;

  // zero out[] + cnt[] in one dispatch
  zero_kernel<<<2048, 256, 0, stream>>>((float4*)d_out, out_size / 4,
                                        (float4*)cnt, N / 4);

  node_gate_kernel<<<N / 4, 256, 0, stream>>>(h, W_head, W_tail, eh, et, N);
  {
    int blocks = 2048;  // R15-verified best (4096 regressed)
    int nwaves = blocks * 4;
    edge_logit_kernel<<<blocks, 256, 0, stream>>>(r, W_rel, eh, et, src, dst,
                                                  cnt, bins, E, nwaves, npg);
  }
  ft_kernel<<<N / 8, 256, 0, stream>>>(h, bins, cnt, ft, N, npg);
  assign_kernel<<<512, 256, 0, stream>>>(ft, W_fc, b_fc, S, N);
  pmat_kernel<<<N / 8, 256, 0, stream>>>(S, bins, cnt, P, N, npg);

  float* out_f = (float*)d_out;
  const long adj_elems = (long)(B * 128) * (B * 128);
  // h_pool = S^T h
  pool_gemm_part_kernel<<<dim3(8, B, 8), 256, 0, stream>>>(S, h, part, npg, 8);
  pool_reduce_kernel<<<(32 * 16384) / 256, 256, 0, stream>>>(part, out_f + adj_elems,
                                                             (long)128 * 128, 128);
  // adj blocks = P^T S
  pool_gemm_part_kernel<<<dim3(8, B, 8), 256, 0, stream>>>(P, S, part, npg, 8);
  pool_reduce_kernel<<<(32 * 16384) / 256, 256, 0, stream>>>(part, out_f,
                                                             (long)(128 * (B * 128) + 128),
                                                             B * 128);
}